// Round 14
// baseline (225.257 us; speedup 1.0000x reference)
//
#include <hip/hip_runtime.h>
#include <hip/hip_bf16.h>

#define B_ 4
#define U_ 16
#define L_ 128
#define H_ 768
#define M_ 256
#define HID_ 150

typedef _Float16 half8 __attribute__((ext_vector_type(8)));
typedef _Float16 half4t __attribute__((ext_vector_type(4)));
typedef float floatx4 __attribute__((ext_vector_type(4)));
typedef float floatx16 __attribute__((ext_vector_type(16)));

// async global->LDS, 16B per lane; lds dest must be wave-uniform base.
__device__ __forceinline__ void gl_lds16(const _Float16* g, _Float16* l)
{
    __builtin_amdgcn_global_load_lds(
        (const __attribute__((address_space(1))) unsigned int*)g,
        (__attribute__((address_space(3))) unsigned int*)l, 16, 0, 0);
}

// ---------------------------------------------------------------------------
// Kernel 0: fused prepack + pool.
//   blocks [0,1540): prepack weights (coalesced reads; formats HW-verified).
//   blocks [1540,1796): masked mean-pool -> f16 (4 rows/block, 64 thr/row).
// ---------------------------------------------------------------------------
__global__ __launch_bounds__(256) void prep_pool_kernel(
    const float* __restrict__ W1, const float* __restrict__ W2,
    const float* __restrict__ b2, const float* __restrict__ W3,
    const float* __restrict__ hidden, const int* __restrict__ sutt,
    const int* __restrict__ sstart, const int* __restrict__ send,
    _Float16* __restrict__ W1cs, _Float16* __restrict__ W2s,
    _Float16* __restrict__ W1abs, float2* __restrict__ bw,
    _Float16* __restrict__ pooledh)
{
    if (blockIdx.x >= 1540) {   // ---- pool part ----
        const int bm = (blockIdx.x - 1540) * 4 + (threadIdx.x >> 6);
        const int lane = threadIdx.x & 63;
        const int b  = bm >> 8;
        const int u  = sutt[bm];
        const int st = sstart[bm];
        const int en = send[bm];
        const float inv = 1.0f / (float)(en - st);
        const float* src = hidden + ((size_t)(b * U_ + u) * L_) * H_ + lane * 12;
        float4 s[3];
        #pragma unroll
        for (int q = 0; q < 3; ++q) s[q] = make_float4(0.f, 0.f, 0.f, 0.f);
        for (int l = st; l < en; ++l) {
            const float* p = src + (size_t)l * H_;
            #pragma unroll
            for (int q = 0; q < 3; ++q) {
                float4 v = *(const float4*)(p + q * 4);
                s[q].x += v.x; s[q].y += v.y; s[q].z += v.z; s[q].w += v.w;
            }
        }
        _Float16* gp = pooledh + (size_t)bm * H_ + lane * 12;
        #pragma unroll
        for (int q = 0; q < 3; ++q) {
            half4t hv;
            hv[0] = (_Float16)(s[q].x * inv); hv[1] = (_Float16)(s[q].y * inv);
            hv[2] = (_Float16)(s[q].z * inv); hv[3] = (_Float16)(s[q].w * inv);
            *(half4t*)(gp + q * 4) = hv;
        }
        return;
    }
    // ---- prep part ----
    int idx = blockIdx.x * 256 + threadIdx.x;
    if (blockIdx.x == 0 && threadIdx.x < 160) {
        int n = threadIdx.x;
        bw[n] = (n < HID_) ? make_float2(b2[n], W3[n]) : make_float2(0.f, 0.f);
    }
    if (idx < 122880) {   // W1cs: idx = k*160 + n (n-inner -> coalesced read)
        int k = idx / 160, n = idx - k * 160;
        float v = (n < HID_) ? W1[(size_t)(2 * H_ + k) * HID_ + n] : 0.f;
        W1cs[(k >> 4) * 2560 + (n >> 5) * 512 +
             (((n & 31) | (((k >> 3) & 1) << 5)) << 3) + (k & 7)] = (_Float16)v;
        return;
    }
    idx -= 122880;
    if (idx < 25600) {    // W2s: idx = k*160 + n
        int k = idx / 160, n = idx - k * 160;
        float v = (k < HID_ && n < HID_) ? W2[(size_t)k * HID_ + n] : 0.f;
        W2s[(k >> 4) * 2560 + (n >> 5) * 512 +
            (((n & 31) | (((k >> 3) & 1) << 5)) << 3) + (k & 7)] = (_Float16)v;
        return;
    }
    idx -= 25600;
    if (idx < 245760) {   // W1abs: idx = k*320 + n
        int k = idx / 320, n = idx - k * 320;
        float v = 0.f;
        if (n < HID_) v = W1[(size_t)k * HID_ + n];
        else if (n >= 160 && n < 160 + HID_) v = W1[(size_t)(H_ + k) * HID_ + (n - 160)];
        W1abs[(k >> 5) * 10240 + (n >> 4) * 512 +
              (((n & 15) | (((k >> 3) & 3) << 4)) << 3) + (k & 7)] = (_Float16)v;
    }
}

// ---------------------------------------------------------------------------
// Kernel 2: hi/hj projection (R11-measured config: 64 blocks x 256 thr).
// hiF[row][160] (b1 folded), hjT[160][1024] transposed.
// ---------------------------------------------------------------------------
__global__ __launch_bounds__(256) void hihj_kernel(
    const _Float16* __restrict__ pooledh, const float* __restrict__ b1,
    const _Float16* __restrict__ W1abs,
    float* __restrict__ hiF, float* __restrict__ hjT)
{
    __shared__ __align__(16) _Float16 spool[16 * 776];
    const int blk = blockIdx.x;
    const int tid = threadIdx.x;
    for (int e = tid; e < 16 * 96; e += 256) {
        int r = e / 96, c = e - r * 96;
        *(half8*)&spool[r * 776 + c * 8] =
            *(const half8*)&pooledh[(size_t)(blk * 16 + r) * H_ + c * 8];
    }
    __syncthreads();

    const int w = tid >> 6, lane = tid & 63;
    const int g = lane >> 4, l15 = lane & 15;
    floatx4 acc[5];
    #pragma unroll
    for (int u5 = 0; u5 < 5; ++u5) acc[u5] = (floatx4){0.f, 0.f, 0.f, 0.f};
    const _Float16* aB = &spool[l15 * 776 + g * 8];
    for (int kc = 0; kc < 24; ++kc) {
        half8 av = *(const half8*)(aB + kc * 32);
        #pragma unroll
        for (int u5 = 0; u5 < 5; ++u5) {
            const int u = w * 5 + u5;
            half8 bv = *(const half8*)(W1abs + (size_t)((kc * 20 + u) * 64 + lane) * 8);
            acc[u5] = __builtin_amdgcn_mfma_f32_16x16x32_f16(av, bv, acc[u5], 0, 0, 0);
        }
    }
    const int row0 = blk * 16 + g * 4;
    #pragma unroll
    for (int u5 = 0; u5 < 5; ++u5) {
        const int n = (w * 5 + u5) * 16 + l15;
        if (n < HID_) {
            float b1v = b1[n];
            #pragma unroll
            for (int r = 0; r < 4; ++r)
                hiF[(size_t)(row0 + r) * 160 + n] = acc[u5][r] + b1v;
        } else if (n >= 160 && n < 160 + HID_) {
            *(float4*)&hjT[(size_t)(n - 160) * 1024 + row0] =
                make_float4(acc[u5][0], acc[u5][1], acc[u5][2], acc[u5][3]);
        }
    }
}

// ---------------------------------------------------------------------------
// Kernel 3: fused pair MLP (R13-measured structure, VGPR 80, 88us).
//   R14: grid split into 4 dispatches of 576 blocks (qoff param) -- pure
//   partition, same work -- to lower the rocprof top-5 visibility threshold
//   from 88us to ~22us and expose the other kernels' durations.
// C/D 32x32: col=lane&31, row=(reg&3)+8*(reg>>2)+4*(lane>>5).  [R4-verified]
// ---------------------------------------------------------------------------
__global__ __launch_bounds__(128, 3) void pair_mlp_kernel(
    int qoff,
    const _Float16* __restrict__ pooledh,
    const float* __restrict__ hiF, const float* __restrict__ hjT,
    const _Float16* __restrict__ W1cs, const _Float16* __restrict__ W2s,
    const float2* __restrict__ bw, const float* __restrict__ b3,
    float* __restrict__ logits)
{
    __shared__ __align__(16) _Float16 smem[2 * 5440];   // 21760 B

    int q = blockIdx.x + qoff;
    const int b = q / 576;
    int r = q - b * 576;
    int jt = 0;
    while (r >= 128 - 16 * jt) { r -= 128 - 16 * jt; ++jt; }
    const int p = 16 * jt + r;           // i-pair: i in {2p, 2p+1}
    const int i0 = 2 * p, j0 = jt * 32;
    const int bm = b * M_;
    const int w = threadIdx.x >> 6;      // wave 0/1 -> i = i0 + w
    const int lane = threadIdx.x & 63;
    const int c31 = lane & 31;
    const int hw = lane >> 5;            // half-wave 0/1

    _Float16* Wb0 = smem;                // [5120] f16 (10240 B)
    _Float16* Wb1 = smem + 5120;
    _Float16* h1w = smem + w * 5440;     // per-wave 32x170 f16; aliases W bufs

    const _Float16* pjp = pooledh + (size_t)(bm + j0 + c31) * H_ + (hw << 3);
    const _Float16* pip = pooledh + (size_t)(bm + i0 + w) * H_ + (hw << 3);

    floatx16 acc1[5];
    #pragma unroll
    for (int t1 = 0; t1 < 5; ++t1)
        #pragma unroll
        for (int e = 0; e < 16; ++e) acc1[t1][e] = 0.f;

    // ---- prologue: stage W chunk 0; load A chunk 0 ----
    {
        const _Float16* gW = W1cs + (size_t)(5 * w) * 512 + lane * 8;
        #pragma unroll
        for (int c = 0; c < 5; ++c)
            gl_lds16(gW + c * 512, Wb0 + (5 * w + c) * 512);
    }
    half8 Apj0 = *(const half8*)(pjp);
    half8 Apj1 = *(const half8*)(pjp + 16);
    half8 Ai0  = *(const half8*)(pip);
    half8 Ai1  = *(const half8*)(pip + 16);
    __syncthreads();

    // ---- stage 1: K=768, 24 chunks of 32; stage kc+1, compute kc ----
    for (int kc = 0; kc < 24; ++kc) {
        const _Float16* Wcur = (kc & 1) ? Wb1 : Wb0;
        _Float16*       Wnxt = (kc & 1) ? Wb0 : Wb1;
        half8 npj0, npj1, ni0, ni1;
        if (kc < 23) {
            const _Float16* gW = W1cs + (size_t)(kc + 1) * 5120 + (5 * w) * 512 + lane * 8;
            #pragma unroll
            for (int c = 0; c < 5; ++c)
                gl_lds16(gW + c * 512, Wnxt + (5 * w + c) * 512);
            const int kb = (kc + 1) * 32;
            npj0 = *(const half8*)(pjp + kb);
            npj1 = *(const half8*)(pjp + kb + 16);
            ni0  = *(const half8*)(pip + kb);
            ni1  = *(const half8*)(pip + kb + 16);
        }
        {   // h = 0: frags 0..4
            half8 a = Ai0 * Apj0;
            #pragma unroll
            for (int t1 = 0; t1 < 5; ++t1) {
                half8 wf = *(const half8*)&Wcur[t1 * 512 + lane * 8];
                acc1[t1] = __builtin_amdgcn_mfma_f32_32x32x16_f16(wf, a, acc1[t1], 0, 0, 0);
            }
        }
        {   // h = 1: frags 5..9
            half8 a = Ai1 * Apj1;
            #pragma unroll
            for (int t1 = 0; t1 < 5; ++t1) {
                half8 wf = *(const half8*)&Wcur[(5 + t1) * 512 + lane * 8];
                acc1[t1] = __builtin_amdgcn_mfma_f32_32x32x16_f16(wf, a, acc1[t1], 0, 0, 0);
            }
        }
        if (kc < 23) { Apj0 = npj0; Apj1 = npj1; Ai0 = ni0; Ai1 = ni1; }
        __syncthreads();   // drains vmcnt (staged W + A loads); gates dbuf swap
    }
    // After final barrier every wave is done reading W bufs -> h1 may alias.

    // ---- epilogue 1: h1 = relu(acc + hiF + hjT) -> per-wave LDS ----
    const int jcol = bm + j0 + c31;
    #pragma unroll
    for (int t1 = 0; t1 < 5; ++t1) {
        #pragma unroll
        for (int qd = 0; qd < 4; ++qd) {
            const int n1 = t1 * 32 + 8 * qd + 4 * hw;
            float hj0 = hjT[(size_t)(n1 + 0) * 1024 + jcol];
            float hj1 = hjT[(size_t)(n1 + 1) * 1024 + jcol];
            float hj2 = hjT[(size_t)(n1 + 2) * 1024 + jcol];
            float hj3 = hjT[(size_t)(n1 + 3) * 1024 + jcol];
            float4 hiv = *(const float4*)&hiF[(size_t)(bm + i0 + w) * 160 + n1];
            half4t hv;
            hv[0] = (_Float16)fmaxf(acc1[t1][4 * qd + 0] + hiv.x + hj0, 0.f);
            hv[1] = (_Float16)fmaxf(acc1[t1][4 * qd + 1] + hiv.y + hj1, 0.f);
            hv[2] = (_Float16)fmaxf(acc1[t1][4 * qd + 2] + hiv.z + hj2, 0.f);
            hv[3] = (_Float16)fmaxf(acc1[t1][4 * qd + 3] + hiv.w + hj3, 0.f);
            *(half4t*)&h1w[c31 * 170 + n1] = hv;
        }
    }
    __syncthreads();

    // ---- stage 2: acc2 = W2s @ h1 (K=160), 2-deep pipelined ----
    const float b3v = b3[0];
    floatx16 acc2[5];
    #pragma unroll
    for (int t2 = 0; t2 < 5; ++t2)
        #pragma unroll
        for (int e = 0; e < 16; ++e) acc2[t2][e] = 0.f;

    half8 W2b[2][5], h1b[2];
    #pragma unroll
    for (int c = 0; c < 2; ++c) {
        const _Float16* wb = W2s + (size_t)(c * 5) * 512 + lane * 8;
        #pragma unroll
        for (int t2 = 0; t2 < 5; ++t2) W2b[c][t2] = *(const half8*)(wb + t2 * 512);
        h1b[c] = *(const half8*)&h1w[c31 * 170 + c * 16 + hw * 8];
    }
    for (int kc2 = 0; kc2 < 10; ++kc2) {
        const int cur = kc2 & 1;
        half8 nw[5], nh;
        if (kc2 < 8) {
            const _Float16* wb = W2s + (size_t)((kc2 + 2) * 5) * 512 + lane * 8;
            #pragma unroll
            for (int t2 = 0; t2 < 5; ++t2) nw[t2] = *(const half8*)(wb + t2 * 512);
            nh = *(const half8*)&h1w[c31 * 170 + (kc2 + 2) * 16 + hw * 8];
        }
        #pragma unroll
        for (int t2 = 0; t2 < 5; ++t2)
            acc2[t2] = __builtin_amdgcn_mfma_f32_32x32x16_f16(
                W2b[cur][t2], h1b[cur], acc2[t2], 0, 0, 0);
        if (kc2 < 8) {
            #pragma unroll
            for (int t2 = 0; t2 < 5; ++t2) W2b[cur][t2] = nw[t2];
            h1b[cur] = nh;
        }
    }

    // ---- stage 3: s = relu(acc2 + b2) . W3, half-wave reduce, write ----
    float sown = 0.f;
    #pragma unroll
    for (int t2 = 0; t2 < 5; ++t2) {
        #pragma unroll
        for (int qd = 0; qd < 4; ++qd) {
            const int n2 = t2 * 32 + 8 * qd + 4 * hw;
            float4 bw01 = *(const float4*)&bw[n2];
            float4 bw23 = *(const float4*)&bw[n2 + 2];
            sown += fmaxf(acc2[t2][4 * qd + 0] + bw01.x, 0.f) * bw01.y;
            sown += fmaxf(acc2[t2][4 * qd + 1] + bw01.z, 0.f) * bw01.w;
            sown += fmaxf(acc2[t2][4 * qd + 2] + bw23.x, 0.f) * bw23.y;
            sown += fmaxf(acc2[t2][4 * qd + 3] + bw23.z, 0.f) * bw23.w;
        }
    }
    float s = sown + __shfl_xor(sown, 32);
    const int i = i0 + w;
    const int j = j0 + c31;
    if (lane < 32 && j < i)
        logits[(size_t)(bm + i) * M_ + j] = s + b3v;
}

// ---------------------------------------------------------------------------
// Kernel 4: loss. 1 wave/row, shuffle-only (no LDS, no barriers).
// Lane handles j = q*64 + lane, q<4.
// ---------------------------------------------------------------------------
__global__ __launch_bounds__(64) void loss_kernel(
    const float* __restrict__ logits, const float* __restrict__ labels,
    float* __restrict__ out)
{
    const int bm = blockIdx.x;
    const int i  = bm & (M_ - 1);
    const int lane = threadIdx.x;

    float val[4];
    #pragma unroll
    for (int qq = 0; qq < 4; ++qq) {
        const int j = qq * 64 + lane;
        val[qq] = (j < i) ? logits[(size_t)bm * M_ + j]
                          : ((j == i) ? 0.0f : -1e30f);
    }
    float m = fmaxf(fmaxf(val[0], val[1]), fmaxf(val[2], val[3]));
    #pragma unroll
    for (int off = 32; off >= 1; off >>= 1) m = fmaxf(m, __shfl_xor(m, off));

    float s = 0.f;
    float e[4];
    #pragma unroll
    for (int qq = 0; qq < 4; ++qq) {
        const int j = qq * 64 + lane;
        e[qq] = (j <= i) ? expf(val[qq] - m) : 0.0f;
        s += e[qq];
    }
    #pragma unroll
    for (int off = 32; off >= 1; off >>= 1) s += __shfl_xor(s, off);
    const float inv_s = 1.0f / s;

    float rs = 0.f;
    #pragma unroll
    for (int qq = 0; qq < 4; ++qq) {
        const int j = qq * 64 + lane;
        float prob = (j <= i) ? (e[qq] * inv_s) : -1000.0f;
        float tv = prob * labels[(size_t)bm * M_ + j];
        rs += fminf(fmaxf(tv, 1e-8f), 1.0f - 1e-8f);
    }
    #pragma unroll
    for (int off = 32; off >= 1; off >>= 1) rs += __shfl_xor(rs, off);

    if (lane == 0) atomicAdd(out, -logf(rs));
}

// ---------------------------------------------------------------------------
extern "C" void kernel_launch(void* const* d_in, const int* in_sizes, int n_in,
                              void* d_out, int out_size, void* d_ws, size_t ws_size,
                              hipStream_t stream)
{
    const float* hidden = (const float*)d_in[0];
    const int*   sutt   = (const int*)d_in[1];
    const int*   sstart = (const int*)d_in[2];
    const int*   send   = (const int*)d_in[3];
    const float* labels = (const float*)d_in[4];
    const float* W1     = (const float*)d_in[5];
    const float* b1     = (const float*)d_in[6];
    const float* W2     = (const float*)d_in[7];
    const float* b2     = (const float*)d_in[8];
    const float* W3     = (const float*)d_in[9];
    const float* b3     = (const float*)d_in[10];

    float* ws = (float*)d_ws;
    float*    hiF     = ws;                          // [1024][160]
    float*    hjT     = ws + 163840;                 // [160][1024]
    float*    logits  = ws + 327680;                 // 262144
    float2*   bw      = (float2*)(ws + 589824);      // 160 float2
    _Float16* pooledh = (_Float16*)(ws + 590144);    // 786432 f16
    _Float16* W1cs    = (_Float16*)(ws + 983360);    // 122880 f16
    _Float16* W2s     = (_Float16*)(ws + 1106240);   // 25600 f16
    _Float16* W1abs   = (_Float16*)(ws + 1119040);   // 245760 f16
    float* out = (float*)d_out;

    hipMemsetAsync(d_out, 0, sizeof(float), stream);

    prep_pool_kernel<<<dim3(1796), 256, 0, stream>>>(
        W1, W2, b2, W3, hidden, sutt, sstart, send,
        W1cs, W2s, W1abs, bw, pooledh);
    hihj_kernel<<<dim3(64), 256, 0, stream>>>(pooledh, b1, W1abs, hiF, hjT);
    pair_mlp_kernel<<<dim3(576), 128, 0, stream>>>(0,    pooledh, hiF, hjT,
                                                   W1cs, W2s, bw, b3, logits);
    pair_mlp_kernel<<<dim3(576), 128, 0, stream>>>(576,  pooledh, hiF, hjT,
                                                   W1cs, W2s, bw, b3, logits);
    pair_mlp_kernel<<<dim3(576), 128, 0, stream>>>(1152, pooledh, hiF, hjT,
                                                   W1cs, W2s, bw, b3, logits);
    pair_mlp_kernel<<<dim3(576), 128, 0, stream>>>(1728, pooledh, hiF, hjT,
                                                   W1cs, W2s, bw, b3, logits);
    loss_kernel<<<dim3(B_ * M_), 64, 0, stream>>>(logits, labels, out);
}

// Round 15
// 192.591 us; speedup vs baseline: 1.1696x; 1.1696x over previous
//
#include <hip/hip_runtime.h>
#include <hip/hip_bf16.h>

#define B_ 4
#define U_ 16
#define L_ 128
#define H_ 768
#define M_ 256
#define HID_ 150

typedef _Float16 half8 __attribute__((ext_vector_type(8)));
typedef _Float16 half4t __attribute__((ext_vector_type(4)));
typedef float floatx4 __attribute__((ext_vector_type(4)));
typedef float floatx16 __attribute__((ext_vector_type(16)));

// async global->LDS, 16B per lane; lds dest must be wave-uniform base.
__device__ __forceinline__ void gl_lds16(const _Float16* g, _Float16* l)
{
    __builtin_amdgcn_global_load_lds(
        (const __attribute__((address_space(1))) unsigned int*)g,
        (__attribute__((address_space(3))) unsigned int*)l, 16, 0, 0);
}

// ---------------------------------------------------------------------------
// Kernel 0: fused prepack + pool.
//   blocks [0,1540): prepack weights (coalesced reads; formats HW-verified).
//   blocks [1540,1796): masked mean-pool -> f16 (4 rows/block, 64 thr/row).
// ---------------------------------------------------------------------------
__global__ __launch_bounds__(256) void prep_pool_kernel(
    const float* __restrict__ W1, const float* __restrict__ W2,
    const float* __restrict__ b2, const float* __restrict__ W3,
    const float* __restrict__ hidden, const int* __restrict__ sutt,
    const int* __restrict__ sstart, const int* __restrict__ send,
    _Float16* __restrict__ W1cs, _Float16* __restrict__ W2s,
    _Float16* __restrict__ W1abs, float2* __restrict__ bw,
    _Float16* __restrict__ pooledh)
{
    if (blockIdx.x >= 1540) {   // ---- pool part ----
        const int bm = (blockIdx.x - 1540) * 4 + (threadIdx.x >> 6);
        const int lane = threadIdx.x & 63;
        const int b  = bm >> 8;
        const int u  = sutt[bm];
        const int st = sstart[bm];
        const int en = send[bm];
        const float inv = 1.0f / (float)(en - st);
        const float* src = hidden + ((size_t)(b * U_ + u) * L_) * H_ + lane * 12;
        float4 s[3];
        #pragma unroll
        for (int q = 0; q < 3; ++q) s[q] = make_float4(0.f, 0.f, 0.f, 0.f);
        for (int l = st; l < en; ++l) {
            const float* p = src + (size_t)l * H_;
            #pragma unroll
            for (int q = 0; q < 3; ++q) {
                float4 v = *(const float4*)(p + q * 4);
                s[q].x += v.x; s[q].y += v.y; s[q].z += v.z; s[q].w += v.w;
            }
        }
        _Float16* gp = pooledh + (size_t)bm * H_ + lane * 12;
        #pragma unroll
        for (int q = 0; q < 3; ++q) {
            half4t hv;
            hv[0] = (_Float16)(s[q].x * inv); hv[1] = (_Float16)(s[q].y * inv);
            hv[2] = (_Float16)(s[q].z * inv); hv[3] = (_Float16)(s[q].w * inv);
            *(half4t*)(gp + q * 4) = hv;
        }
        return;
    }
    // ---- prep part ----
    int idx = blockIdx.x * 256 + threadIdx.x;
    if (blockIdx.x == 0 && threadIdx.x < 160) {
        int n = threadIdx.x;
        bw[n] = (n < HID_) ? make_float2(b2[n], W3[n]) : make_float2(0.f, 0.f);
    }
    if (idx < 122880) {   // W1cs: idx = k*160 + n (n-inner -> coalesced read)
        int k = idx / 160, n = idx - k * 160;
        float v = (n < HID_) ? W1[(size_t)(2 * H_ + k) * HID_ + n] : 0.f;
        W1cs[(k >> 4) * 2560 + (n >> 5) * 512 +
             (((n & 31) | (((k >> 3) & 1) << 5)) << 3) + (k & 7)] = (_Float16)v;
        return;
    }
    idx -= 122880;
    if (idx < 25600) {    // W2s: idx = k*160 + n
        int k = idx / 160, n = idx - k * 160;
        float v = (k < HID_ && n < HID_) ? W2[(size_t)k * HID_ + n] : 0.f;
        W2s[(k >> 4) * 2560 + (n >> 5) * 512 +
            (((n & 31) | (((k >> 3) & 1) << 5)) << 3) + (k & 7)] = (_Float16)v;
        return;
    }
    idx -= 25600;
    if (idx < 245760) {   // W1abs: idx = k*320 + n
        int k = idx / 320, n = idx - k * 320;
        float v = 0.f;
        if (n < HID_) v = W1[(size_t)k * HID_ + n];
        else if (n >= 160 && n < 160 + HID_) v = W1[(size_t)(H_ + k) * HID_ + (n - 160)];
        W1abs[(k >> 5) * 10240 + (n >> 4) * 512 +
              (((n & 15) | (((k >> 3) & 3) << 4)) << 3) + (k & 7)] = (_Float16)v;
    }
}

// ---------------------------------------------------------------------------
// Kernel 2: hi/hj projection + pooled-j fragment prepack.
//   blocks [0,64): hihj (R11-measured config).
//   blocks [64,448): pack pjF: fragment-linear pooled-j so pair's A-loads
//     are coalesced 16B/lane (was 32 cache lines per load at stride 1536B).
//   pjF layout: idx = ((g*24+kc)*2+chunk)*64 + l (g=b*8+jt); 8 f16 each:
//     pjF[idx*8] = pooledh[row(g,l)*768 + kc*32 + chunk*16 + (l>>5)*8]
// ---------------------------------------------------------------------------
__global__ __launch_bounds__(256) void hihj_kernel(
    const _Float16* __restrict__ pooledh, const float* __restrict__ b1,
    const _Float16* __restrict__ W1abs,
    float* __restrict__ hiF, float* __restrict__ hjT,
    _Float16* __restrict__ pjF)
{
    if (blockIdx.x >= 64) {   // ---- pjF pack: 384 blocks x 256 chunk-moves --
        const int idx = (blockIdx.x - 64) * 256 + threadIdx.x;  // [0, 98304)
        const int g = idx / 3072, rem = idx - g * 3072;
        const int kc = rem >> 7, rem2 = rem & 127;
        const int chunk = rem2 >> 6, l = rem2 & 63;
        const int row = (g >> 3) * 256 + (g & 7) * 32 + (l & 31);
        const int col = kc * 32 + chunk * 16 + ((l >> 5) << 3);
        *(half8*)&pjF[(size_t)idx * 8] =
            *(const half8*)&pooledh[(size_t)row * H_ + col];
        return;
    }
    __shared__ __align__(16) _Float16 spool[16 * 776];
    const int blk = blockIdx.x;
    const int tid = threadIdx.x;
    for (int e = tid; e < 16 * 96; e += 256) {
        int r = e / 96, c = e - r * 96;
        *(half8*)&spool[r * 776 + c * 8] =
            *(const half8*)&pooledh[(size_t)(blk * 16 + r) * H_ + c * 8];
    }
    __syncthreads();

    const int w = tid >> 6, lane = tid & 63;
    const int g = lane >> 4, l15 = lane & 15;
    floatx4 acc[5];
    #pragma unroll
    for (int u5 = 0; u5 < 5; ++u5) acc[u5] = (floatx4){0.f, 0.f, 0.f, 0.f};
    const _Float16* aB = &spool[l15 * 776 + g * 8];
    for (int kc = 0; kc < 24; ++kc) {
        half8 av = *(const half8*)(aB + kc * 32);
        #pragma unroll
        for (int u5 = 0; u5 < 5; ++u5) {
            const int u = w * 5 + u5;
            half8 bv = *(const half8*)(W1abs + (size_t)((kc * 20 + u) * 64 + lane) * 8);
            acc[u5] = __builtin_amdgcn_mfma_f32_16x16x32_f16(av, bv, acc[u5], 0, 0, 0);
        }
    }
    const int row0 = blk * 16 + g * 4;
    #pragma unroll
    for (int u5 = 0; u5 < 5; ++u5) {
        const int n = (w * 5 + u5) * 16 + l15;
        if (n < HID_) {
            float b1v = b1[n];
            #pragma unroll
            for (int r = 0; r < 4; ++r)
                hiF[(size_t)(row0 + r) * 160 + n] = acc[u5][r] + b1v;
        } else if (n >= 160 && n < 160 + HID_) {
            *(float4*)&hjT[(size_t)(n - 160) * 1024 + row0] =
                make_float4(acc[u5][0], acc[u5][1], acc[u5][2], acc[u5][3]);
        }
    }
}

// ---------------------------------------------------------------------------
// Kernel 3: fused pair MLP (R13-measured structure) + coalesced pjF A-loads.
//   R14 finding: harness ws-poison fills = ~88us of the window (untouchable);
//   4-way split reverted (+20us cost). This round's lever: pj gather was 32
//   cache lines/load (rows stride 1536B); pjF prepack makes it 16B/lane
//   coalesced and removes 16x redundant j-row reads across blocks.
// C/D 32x32: col=lane&31, row=(reg&3)+8*(reg>>2)+4*(lane>>5).  [R4-verified]
// ---------------------------------------------------------------------------
__global__ __launch_bounds__(128, 3) void pair_mlp_kernel(
    const _Float16* __restrict__ pooledh, const _Float16* __restrict__ pjF,
    const float* __restrict__ hiF, const float* __restrict__ hjT,
    const _Float16* __restrict__ W1cs, const _Float16* __restrict__ W2s,
    const float2* __restrict__ bw, const float* __restrict__ b3,
    float* __restrict__ logits)
{
    __shared__ __align__(16) _Float16 smem[2 * 5440];   // 21760 B

    int q = blockIdx.x;
    const int b = q / 576;
    int r = q - b * 576;
    int jt = 0;
    while (r >= 128 - 16 * jt) { r -= 128 - 16 * jt; ++jt; }
    const int p = 16 * jt + r;           // i-pair: i in {2p, 2p+1}
    const int i0 = 2 * p, j0 = jt * 32;
    const int bm = b * M_;
    const int w = threadIdx.x >> 6;      // wave 0/1 -> i = i0 + w
    const int lane = threadIdx.x & 63;
    const int c31 = lane & 31;
    const int hw = lane >> 5;            // half-wave 0/1

    _Float16* Wb0 = smem;                // [5120] f16 (10240 B)
    _Float16* Wb1 = smem + 5120;
    _Float16* h1w = smem + w * 5440;     // per-wave 32x170 f16; aliases W bufs

    const _Float16* pjb = pjF + (size_t)(b * 8 + jt) * 24576 + lane * 8;
    const _Float16* pip = pooledh + (size_t)(bm + i0 + w) * H_ + (hw << 3);

    floatx16 acc1[5];
    #pragma unroll
    for (int t1 = 0; t1 < 5; ++t1)
        #pragma unroll
        for (int e = 0; e < 16; ++e) acc1[t1][e] = 0.f;

    // ---- prologue: stage W chunk 0; load A chunk 0 ----
    {
        const _Float16* gW = W1cs + (size_t)(5 * w) * 512 + lane * 8;
        #pragma unroll
        for (int c = 0; c < 5; ++c)
            gl_lds16(gW + c * 512, Wb0 + (5 * w + c) * 512);
    }
    half8 Apj0 = *(const half8*)(pjb);
    half8 Apj1 = *(const half8*)(pjb + 512);
    half8 Ai0  = *(const half8*)(pip);
    half8 Ai1  = *(const half8*)(pip + 16);
    __syncthreads();

    // ---- stage 1: K=768, 24 chunks of 32; stage kc+1, compute kc ----
    for (int kc = 0; kc < 24; ++kc) {
        const _Float16* Wcur = (kc & 1) ? Wb1 : Wb0;
        _Float16*       Wnxt = (kc & 1) ? Wb0 : Wb1;
        half8 npj0, npj1, ni0, ni1;
        if (kc < 23) {
            const _Float16* gW = W1cs + (size_t)(kc + 1) * 5120 + (5 * w) * 512 + lane * 8;
            #pragma unroll
            for (int c = 0; c < 5; ++c)
                gl_lds16(gW + c * 512, Wnxt + (5 * w + c) * 512);
            npj0 = *(const half8*)(pjb + (kc + 1) * 1024);
            npj1 = *(const half8*)(pjb + (kc + 1) * 1024 + 512);
            const int kb = (kc + 1) * 32;
            ni0  = *(const half8*)(pip + kb);
            ni1  = *(const half8*)(pip + kb + 16);
        }
        {   // h = 0: frags 0..4
            half8 a = Ai0 * Apj0;
            #pragma unroll
            for (int t1 = 0; t1 < 5; ++t1) {
                half8 wf = *(const half8*)&Wcur[t1 * 512 + lane * 8];
                acc1[t1] = __builtin_amdgcn_mfma_f32_32x32x16_f16(wf, a, acc1[t1], 0, 0, 0);
            }
        }
        {   // h = 1: frags 5..9
            half8 a = Ai1 * Apj1;
            #pragma unroll
            for (int t1 = 0; t1 < 5; ++t1) {
                half8 wf = *(const half8*)&Wcur[(5 + t1) * 512 + lane * 8];
                acc1[t1] = __builtin_amdgcn_mfma_f32_32x32x16_f16(wf, a, acc1[t1], 0, 0, 0);
            }
        }
        if (kc < 23) { Apj0 = npj0; Apj1 = npj1; Ai0 = ni0; Ai1 = ni1; }
        __syncthreads();   // drains vmcnt (staged W + A loads); gates dbuf swap
    }
    // After final barrier every wave is done reading W bufs -> h1 may alias.

    // ---- epilogue 1: h1 = relu(acc + hiF + hjT) -> per-wave LDS ----
    const int jcol = bm + j0 + c31;
    #pragma unroll
    for (int t1 = 0; t1 < 5; ++t1) {
        #pragma unroll
        for (int qd = 0; qd < 4; ++qd) {
            const int n1 = t1 * 32 + 8 * qd + 4 * hw;
            float hj0 = hjT[(size_t)(n1 + 0) * 1024 + jcol];
            float hj1 = hjT[(size_t)(n1 + 1) * 1024 + jcol];
            float hj2 = hjT[(size_t)(n1 + 2) * 1024 + jcol];
            float hj3 = hjT[(size_t)(n1 + 3) * 1024 + jcol];
            float4 hiv = *(const float4*)&hiF[(size_t)(bm + i0 + w) * 160 + n1];
            half4t hv;
            hv[0] = (_Float16)fmaxf(acc1[t1][4 * qd + 0] + hiv.x + hj0, 0.f);
            hv[1] = (_Float16)fmaxf(acc1[t1][4 * qd + 1] + hiv.y + hj1, 0.f);
            hv[2] = (_Float16)fmaxf(acc1[t1][4 * qd + 2] + hiv.z + hj2, 0.f);
            hv[3] = (_Float16)fmaxf(acc1[t1][4 * qd + 3] + hiv.w + hj3, 0.f);
            *(half4t*)&h1w[c31 * 170 + n1] = hv;
        }
    }
    __syncthreads();

    // ---- stage 2: acc2 = W2s @ h1 (K=160), 2-deep pipelined ----
    const float b3v = b3[0];
    floatx16 acc2[5];
    #pragma unroll
    for (int t2 = 0; t2 < 5; ++t2)
        #pragma unroll
        for (int e = 0; e < 16; ++e) acc2[t2][e] = 0.f;

    half8 W2b[2][5], h1b[2];
    #pragma unroll
    for (int c = 0; c < 2; ++c) {
        const _Float16* wb = W2s + (size_t)(c * 5) * 512 + lane * 8;
        #pragma unroll
        for (int t2 = 0; t2 < 5; ++t2) W2b[c][t2] = *(const half8*)(wb + t2 * 512);
        h1b[c] = *(const half8*)&h1w[c31 * 170 + c * 16 + hw * 8];
    }
    for (int kc2 = 0; kc2 < 10; ++kc2) {
        const int cur = kc2 & 1;
        half8 nw[5], nh;
        if (kc2 < 8) {
            const _Float16* wb = W2s + (size_t)((kc2 + 2) * 5) * 512 + lane * 8;
            #pragma unroll
            for (int t2 = 0; t2 < 5; ++t2) nw[t2] = *(const half8*)(wb + t2 * 512);
            nh = *(const half8*)&h1w[c31 * 170 + (kc2 + 2) * 16 + hw * 8];
        }
        #pragma unroll
        for (int t2 = 0; t2 < 5; ++t2)
            acc2[t2] = __builtin_amdgcn_mfma_f32_32x32x16_f16(
                W2b[cur][t2], h1b[cur], acc2[t2], 0, 0, 0);
        if (kc2 < 8) {
            #pragma unroll
            for (int t2 = 0; t2 < 5; ++t2) W2b[cur][t2] = nw[t2];
            h1b[cur] = nh;
        }
    }

    // ---- stage 3: s = relu(acc2 + b2) . W3, half-wave reduce, write ----
    float sown = 0.f;
    #pragma unroll
    for (int t2 = 0; t2 < 5; ++t2) {
        #pragma unroll
        for (int qd = 0; qd < 4; ++qd) {
            const int n2 = t2 * 32 + 8 * qd + 4 * hw;
            float4 bw01 = *(const float4*)&bw[n2];
            float4 bw23 = *(const float4*)&bw[n2 + 2];
            sown += fmaxf(acc2[t2][4 * qd + 0] + bw01.x, 0.f) * bw01.y;
            sown += fmaxf(acc2[t2][4 * qd + 1] + bw01.z, 0.f) * bw01.w;
            sown += fmaxf(acc2[t2][4 * qd + 2] + bw23.x, 0.f) * bw23.y;
            sown += fmaxf(acc2[t2][4 * qd + 3] + bw23.z, 0.f) * bw23.w;
        }
    }
    float s = sown + __shfl_xor(sown, 32);
    const int i = i0 + w;
    const int j = j0 + c31;
    if (lane < 32 && j < i)
        logits[(size_t)(bm + i) * M_ + j] = s + b3v;
}

// ---------------------------------------------------------------------------
// Kernel 4: loss. 1 wave/row, shuffle-only (no LDS, no barriers).
// ---------------------------------------------------------------------------
__global__ __launch_bounds__(64) void loss_kernel(
    const float* __restrict__ logits, const float* __restrict__ labels,
    float* __restrict__ out)
{
    const int bm = blockIdx.x;
    const int i  = bm & (M_ - 1);
    const int lane = threadIdx.x;

    float val[4];
    #pragma unroll
    for (int qq = 0; qq < 4; ++qq) {
        const int j = qq * 64 + lane;
        val[qq] = (j < i) ? logits[(size_t)bm * M_ + j]
                          : ((j == i) ? 0.0f : -1e30f);
    }
    float m = fmaxf(fmaxf(val[0], val[1]), fmaxf(val[2], val[3]));
    #pragma unroll
    for (int off = 32; off >= 1; off >>= 1) m = fmaxf(m, __shfl_xor(m, off));

    float s = 0.f;
    float e[4];
    #pragma unroll
    for (int qq = 0; qq < 4; ++qq) {
        const int j = qq * 64 + lane;
        e[qq] = (j <= i) ? expf(val[qq] - m) : 0.0f;
        s += e[qq];
    }
    #pragma unroll
    for (int off = 32; off >= 1; off >>= 1) s += __shfl_xor(s, off);
    const float inv_s = 1.0f / s;

    float rs = 0.f;
    #pragma unroll
    for (int qq = 0; qq < 4; ++qq) {
        const int j = qq * 64 + lane;
        float prob = (j <= i) ? (e[qq] * inv_s) : -1000.0f;
        float tv = prob * labels[(size_t)bm * M_ + j];
        rs += fminf(fmaxf(tv, 1e-8f), 1.0f - 1e-8f);
    }
    #pragma unroll
    for (int off = 32; off >= 1; off >>= 1) rs += __shfl_xor(rs, off);

    if (lane == 0) atomicAdd(out, -logf(rs));
}

// ---------------------------------------------------------------------------
extern "C" void kernel_launch(void* const* d_in, const int* in_sizes, int n_in,
                              void* d_out, int out_size, void* d_ws, size_t ws_size,
                              hipStream_t stream)
{
    const float* hidden = (const float*)d_in[0];
    const int*   sutt   = (const int*)d_in[1];
    const int*   sstart = (const int*)d_in[2];
    const int*   send   = (const int*)d_in[3];
    const float* labels = (const float*)d_in[4];
    const float* W1     = (const float*)d_in[5];
    const float* b1     = (const float*)d_in[6];
    const float* W2     = (const float*)d_in[7];
    const float* b2     = (const float*)d_in[8];
    const float* W3     = (const float*)d_in[9];
    const float* b3     = (const float*)d_in[10];

    float* ws = (float*)d_ws;
    float*    hiF     = ws;                          // [1024][160]
    float*    hjT     = ws + 163840;                 // [160][1024]
    float*    logits  = ws + 327680;                 // 262144
    float2*   bw      = (float2*)(ws + 589824);      // 160 float2
    _Float16* pooledh = (_Float16*)(ws + 590144);    // 786432 f16
    _Float16* W1cs    = (_Float16*)(ws + 983360);    // 122880 f16
    _Float16* W2s     = (_Float16*)(ws + 1106240);   // 25600 f16
    _Float16* W1abs   = (_Float16*)(ws + 1119040);   // 245760 f16
    _Float16* pjF     = (_Float16*)(ws + 1241920);   // 786432 f16 (1.5 MB)
    float* out = (float*)d_out;

    hipMemsetAsync(d_out, 0, sizeof(float), stream);

    prep_pool_kernel<<<dim3(1796), 256, 0, stream>>>(
        W1, W2, b2, W3, hidden, sutt, sstart, send,
        W1cs, W2s, W1abs, bw, pooledh);
    hihj_kernel<<<dim3(448), 256, 0, stream>>>(pooledh, b1, W1abs,
                                               hiF, hjT, pjF);
    pair_mlp_kernel<<<dim3(576 * B_), 128, 0, stream>>>(pooledh, pjF, hiF, hjT,
                                                        W1cs, W2s, bw, b3, logits);
    loss_kernel<<<dim3(B_ * M_), 64, 0, stream>>>(logits, labels, out);
}

// Round 16
// 190.775 us; speedup vs baseline: 1.1807x; 1.0095x over previous
//
#include <hip/hip_runtime.h>
#include <hip/hip_bf16.h>

#define B_ 4
#define U_ 16
#define L_ 128
#define H_ 768
#define M_ 256
#define HID_ 150

typedef _Float16 half8 __attribute__((ext_vector_type(8)));
typedef _Float16 half4t __attribute__((ext_vector_type(4)));
typedef float floatx4 __attribute__((ext_vector_type(4)));

// async global->LDS, 16B per lane; lds dest must be wave-uniform base.
__device__ __forceinline__ void gl_lds16(const _Float16* g, _Float16* l)
{
    __builtin_amdgcn_global_load_lds(
        (const __attribute__((address_space(1))) unsigned int*)g,
        (__attribute__((address_space(3))) unsigned int*)l, 16, 0, 0);
}

// ---------------------------------------------------------------------------
// Kernel 0: fused prepack + pool.
//   blocks [0,1540): prepack weights into 16x16 A-frag layout (R16):
//     frag idx = ((k>>5)*NT + (n>>4))*512 + (((n&15)|(((k>>3)&3)<<4))<<3) + (k&7)
//     (lane&15 = n-row, (lane>>4)*8 = k-offset -- matches hihj's verified
//      16x16 operand mapping).
//   blocks [1540,1796): masked mean-pool -> f16 (4 rows/block, 64 thr/row).
// ---------------------------------------------------------------------------
__global__ __launch_bounds__(256) void prep_pool_kernel(
    const float* __restrict__ W1, const float* __restrict__ W2,
    const float* __restrict__ b2, const float* __restrict__ W3,
    const float* __restrict__ hidden, const int* __restrict__ sutt,
    const int* __restrict__ sstart, const int* __restrict__ send,
    _Float16* __restrict__ W1cs16, _Float16* __restrict__ W2s16,
    _Float16* __restrict__ W1abs, float2* __restrict__ bw,
    _Float16* __restrict__ pooledh)
{
    if (blockIdx.x >= 1540) {   // ---- pool part ----
        const int bm = (blockIdx.x - 1540) * 4 + (threadIdx.x >> 6);
        const int lane = threadIdx.x & 63;
        const int b  = bm >> 8;
        const int u  = sutt[bm];
        const int st = sstart[bm];
        const int en = send[bm];
        const float inv = 1.0f / (float)(en - st);
        const float* src = hidden + ((size_t)(b * U_ + u) * L_) * H_ + lane * 12;
        float4 s[3];
        #pragma unroll
        for (int q = 0; q < 3; ++q) s[q] = make_float4(0.f, 0.f, 0.f, 0.f);
        for (int l = st; l < en; ++l) {
            const float* p = src + (size_t)l * H_;
            #pragma unroll
            for (int q = 0; q < 3; ++q) {
                float4 v = *(const float4*)(p + q * 4);
                s[q].x += v.x; s[q].y += v.y; s[q].z += v.z; s[q].w += v.w;
            }
        }
        _Float16* gp = pooledh + (size_t)bm * H_ + lane * 12;
        #pragma unroll
        for (int q = 0; q < 3; ++q) {
            half4t hv;
            hv[0] = (_Float16)(s[q].x * inv); hv[1] = (_Float16)(s[q].y * inv);
            hv[2] = (_Float16)(s[q].z * inv); hv[3] = (_Float16)(s[q].w * inv);
            *(half4t*)(gp + q * 4) = hv;
        }
        return;
    }
    // ---- prep part ----
    int idx = blockIdx.x * 256 + threadIdx.x;
    if (blockIdx.x == 0 && threadIdx.x < 160) {
        int n = threadIdx.x;
        bw[n] = (n < HID_) ? make_float2(b2[n], W3[n]) : make_float2(0.f, 0.f);
    }
    if (idx < 122880) {   // W1cs16: idx = k*160 + n (n-inner -> coalesced read)
        int k = idx / 160, n = idx - k * 160;
        float v = (n < HID_) ? W1[(size_t)(2 * H_ + k) * HID_ + n] : 0.f;
        W1cs16[((k >> 5) * 10 + (n >> 4)) * 512 +
               (((n & 15) | (((k >> 3) & 3) << 4)) << 3) + (k & 7)] = (_Float16)v;
        return;
    }
    idx -= 122880;
    if (idx < 25600) {    // W2s16: idx = k*160 + n
        int k = idx / 160, n = idx - k * 160;
        float v = (k < HID_ && n < HID_) ? W2[(size_t)k * HID_ + n] : 0.f;
        W2s16[((k >> 5) * 10 + (n >> 4)) * 512 +
              (((n & 15) | (((k >> 3) & 3) << 4)) << 3) + (k & 7)] = (_Float16)v;
        return;
    }
    idx -= 25600;
    if (idx < 245760) {   // W1abs: idx = k*320 + n
        int k = idx / 320, n = idx - k * 320;
        float v = 0.f;
        if (n < HID_) v = W1[(size_t)k * HID_ + n];
        else if (n >= 160 && n < 160 + HID_) v = W1[(size_t)(H_ + k) * HID_ + (n - 160)];
        W1abs[(k >> 5) * 10240 + (n >> 4) * 512 +
              (((n & 15) | (((k >> 3) & 3) << 4)) << 3) + (k & 7)] = (_Float16)v;
    }
}

// ---------------------------------------------------------------------------
// Kernel 2: hi/hj projection + pooled-j 16x16 B-frag prepack.
//   blocks [0,64): hihj (R11-measured config).
//   blocks [64,448): pjF16: per (b, jb 16-j-block, kc): lane&15 = j-local,
//     (lane>>4)*8 = k-offset; coalesced 16B/lane in pair kernel.
// ---------------------------------------------------------------------------
__global__ __launch_bounds__(256) void hihj_kernel(
    const _Float16* __restrict__ pooledh, const float* __restrict__ b1,
    const _Float16* __restrict__ W1abs,
    float* __restrict__ hiF, float* __restrict__ hjT,
    _Float16* __restrict__ pjF16)
{
    if (blockIdx.x >= 64) {   // ---- pjF16 pack: 384 blocks x 256 half8s ----
        const int idx = (blockIdx.x - 64) * 256 + threadIdx.x;  // [0, 98304)
        const int g16 = idx / 1536, rem = idx - g16 * 1536;     // 24kc x 64ln
        const int kc = rem >> 6, l = rem & 63;
        const int row = (g16 >> 4) * 256 + (g16 & 15) * 16 + (l & 15);
        const int col = kc * 32 + ((l >> 4) << 3);
        *(half8*)&pjF16[(size_t)idx * 8] =
            *(const half8*)&pooledh[(size_t)row * H_ + col];
        return;
    }
    __shared__ __align__(16) _Float16 spool[16 * 776];
    const int blk = blockIdx.x;
    const int tid = threadIdx.x;
    for (int e = tid; e < 16 * 96; e += 256) {
        int r = e / 96, c = e - r * 96;
        *(half8*)&spool[r * 776 + c * 8] =
            *(const half8*)&pooledh[(size_t)(blk * 16 + r) * H_ + c * 8];
    }
    __syncthreads();

    const int w = tid >> 6, lane = tid & 63;
    const int g = lane >> 4, l15 = lane & 15;
    floatx4 acc[5];
    #pragma unroll
    for (int u5 = 0; u5 < 5; ++u5) acc[u5] = (floatx4){0.f, 0.f, 0.f, 0.f};
    const _Float16* aB = &spool[l15 * 776 + g * 8];
    for (int kc = 0; kc < 24; ++kc) {
        half8 av = *(const half8*)(aB + kc * 32);
        #pragma unroll
        for (int u5 = 0; u5 < 5; ++u5) {
            const int u = w * 5 + u5;
            half8 bv = *(const half8*)(W1abs + (size_t)((kc * 20 + u) * 64 + lane) * 8);
            acc[u5] = __builtin_amdgcn_mfma_f32_16x16x32_f16(av, bv, acc[u5], 0, 0, 0);
        }
    }
    const int row0 = blk * 16 + g * 4;
    #pragma unroll
    for (int u5 = 0; u5 < 5; ++u5) {
        const int n = (w * 5 + u5) * 16 + l15;
        if (n < HID_) {
            float b1v = b1[n];
            #pragma unroll
            for (int r = 0; r < 4; ++r)
                hiF[(size_t)(row0 + r) * 160 + n] = acc[u5][r] + b1v;
        } else if (n >= 160 && n < 160 + HID_) {
            *(float4*)&hjT[(size_t)(n - 160) * 1024 + row0] =
                make_float4(acc[u5][0], acc[u5][1], acc[u5][2], acc[u5][3]);
        }
    }
}

// ---------------------------------------------------------------------------
// Kernel 3: fused pair MLP. R16 = 16x16 MFMA occupancy restructure.
//   R15 state: 77.6us, MfmaUtil 23.5%, occ 22.5% -- 160 regs/wave lands in
//   the 256-reg HW slot (m69 quantum) -> 2 waves/SIMD ceiling. 16x16x32
//   shape cuts acc to 10x4 = 40 AGPR: wave = (i-row, j-16-half), block =
//   256thr = 4 waves over same i-pair x 32j tile. Target <=128 unified regs
//   -> 4 waves/SIMD, LDS 21.76KB -> 4 blocks/CU = 50% occ (2.2x).
//   Same W staging via LDS (waves 0,1 stage), same grid/W-traffic as R15.
// C/D 16x16: col=lane&15 (=j), row=(lane>>4)*4+reg (=n-local). [hihj-verified]
// ---------------------------------------------------------------------------
__global__ __launch_bounds__(256, 4) void pair_mlp_kernel(
    const _Float16* __restrict__ pooledh, const _Float16* __restrict__ pjF16,
    const float* __restrict__ hiF, const float* __restrict__ hjT,
    const _Float16* __restrict__ W1cs16, const _Float16* __restrict__ W2s16,
    const float2* __restrict__ bw, const float* __restrict__ b3,
    float* __restrict__ logits)
{
    __shared__ __align__(16) _Float16 smem[10880];   // 21760 B

    int q = blockIdx.x;
    const int b = q / 576;
    int r = q - b * 576;
    int jt = 0;
    while (r >= 128 - 16 * jt) { r -= 128 - 16 * jt; ++jt; }
    const int p = 16 * jt + r;           // i-pair: i in {2p, 2p+1}
    const int i0 = 2 * p, j0 = jt * 32;
    const int bm = b * M_;
    const int w = threadIdx.x >> 6;      // 4 waves: iw = w>>1, jh = w&1
    const int iw = w >> 1, jh = w & 1;
    const int i = i0 + iw;
    const int lane = threadIdx.x & 63;
    const int l15 = lane & 15;
    const int g4 = lane >> 4;            // k-subchunk 0..3

    _Float16* Wb0 = smem;                // [5120] f16 (10240 B)
    _Float16* Wb1 = smem + 5120;
    _Float16* h1w = smem + w * 2720;     // per-wave 16x170 f16; aliases W bufs

    const _Float16* pjb = pjF16 + (size_t)(b * 16 + jt * 2 + jh) * 12288 + lane * 8;
    const _Float16* pip = pooledh + (size_t)(bm + i) * H_ + (g4 << 3);

    floatx4 acc1[10];                    // 40 AGPR
    #pragma unroll
    for (int t = 0; t < 10; ++t) acc1[t] = (floatx4){0.f, 0.f, 0.f, 0.f};

    // ---- prologue: stage W chunk 0 (waves 0,1); load A chunk 0 ----
    if (w < 2) {
        const _Float16* gW = W1cs16 + (size_t)(5 * w) * 512 + lane * 8;
        #pragma unroll
        for (int c = 0; c < 5; ++c)
            gl_lds16(gW + c * 512, Wb0 + (5 * w + c) * 512);
    }
    half8 Apj = *(const half8*)(pjb);
    half8 Api = *(const half8*)(pip);
    __syncthreads();

    // ---- stage 1: K=768, 24 chunks of 32; stage kc+1, compute kc ----
    for (int kc = 0; kc < 24; ++kc) {
        const _Float16* Wcur = (kc & 1) ? Wb1 : Wb0;
        _Float16*       Wnxt = (kc & 1) ? Wb0 : Wb1;
        half8 npj, npi;
        if (kc < 23) {
            if (w < 2) {
                const _Float16* gW = W1cs16 + (size_t)(kc + 1) * 5120
                                     + (5 * w) * 512 + lane * 8;
                #pragma unroll
                for (int c = 0; c < 5; ++c)
                    gl_lds16(gW + c * 512, Wnxt + (5 * w + c) * 512);
            }
            npj = *(const half8*)(pjb + (kc + 1) * 512);
            npi = *(const half8*)(pip + (kc + 1) * 32);
        }
        half8 a = Api * Apj;
        #pragma unroll
        for (int t = 0; t < 10; ++t) {
            half8 wf = *(const half8*)&Wcur[t * 512 + lane * 8];
            acc1[t] = __builtin_amdgcn_mfma_f32_16x16x32_f16(wf, a, acc1[t], 0, 0, 0);
        }
        if (kc < 23) { Apj = npj; Api = npi; }
        __syncthreads();   // drains vmcnt (staged W); gates dbuf swap
    }
    // After final barrier all waves done with W bufs -> h1 may alias.

    // ---- epilogue 1: h1 = relu(acc + hiF + hjT) -> per-wave LDS ----
    const int j = j0 + jh * 16 + l15;
    const int jcol = bm + j;
    #pragma unroll
    for (int t = 0; t < 10; ++t) {
        const int nb = t * 16 + (g4 << 2);
        float hj0 = hjT[(size_t)(nb + 0) * 1024 + jcol];
        float hj1 = hjT[(size_t)(nb + 1) * 1024 + jcol];
        float hj2 = hjT[(size_t)(nb + 2) * 1024 + jcol];
        float hj3 = hjT[(size_t)(nb + 3) * 1024 + jcol];
        float4 hiv = *(const float4*)&hiF[(size_t)(bm + i) * 160 + nb];
        half4t hv;
        hv[0] = (_Float16)fmaxf(acc1[t][0] + hiv.x + hj0, 0.f);
        hv[1] = (_Float16)fmaxf(acc1[t][1] + hiv.y + hj1, 0.f);
        hv[2] = (_Float16)fmaxf(acc1[t][2] + hiv.z + hj2, 0.f);
        hv[3] = (_Float16)fmaxf(acc1[t][3] + hiv.w + hj3, 0.f);
        *(half4t*)&h1w[l15 * 170 + nb] = hv;
    }
    __syncthreads();

    // ---- stage 2: acc2 = W2 @ h1 (K=160, 5 chunks; W2 L2-hot, no dbuf) ----
    const float b3v = b3[0];
    floatx4 acc2[10];
    #pragma unroll
    for (int t2 = 0; t2 < 10; ++t2) acc2[t2] = (floatx4){0.f, 0.f, 0.f, 0.f};
    for (int kc2 = 0; kc2 < 5; ++kc2) {
        half8 hb = *(const half8*)&h1w[l15 * 170 + kc2 * 32 + (g4 << 3)];
        #pragma unroll
        for (int t2 = 0; t2 < 10; ++t2) {
            half8 wf = *(const half8*)(W2s16 + (size_t)(kc2 * 10 + t2) * 512 + lane * 8);
            acc2[t2] = __builtin_amdgcn_mfma_f32_16x16x32_f16(wf, hb, acc2[t2], 0, 0, 0);
        }
    }

    // ---- stage 3: s = relu(acc2 + b2) . W3, cross-k-group reduce, write ----
    float sown = 0.f;
    #pragma unroll
    for (int t2 = 0; t2 < 10; ++t2) {
        const int n2 = t2 * 16 + (g4 << 2);
        float4 bw01 = *(const float4*)&bw[n2];
        float4 bw23 = *(const float4*)&bw[n2 + 2];
        sown += fmaxf(acc2[t2][0] + bw01.x, 0.f) * bw01.y;
        sown += fmaxf(acc2[t2][1] + bw01.z, 0.f) * bw01.w;
        sown += fmaxf(acc2[t2][2] + bw23.x, 0.f) * bw23.y;
        sown += fmaxf(acc2[t2][3] + bw23.z, 0.f) * bw23.w;
    }
    float s = sown;
    s += __shfl_xor(s, 16);
    s += __shfl_xor(s, 32);
    if (lane < 16 && j < i)
        logits[(size_t)(bm + i) * M_ + j] = s + b3v;
}

// ---------------------------------------------------------------------------
// Kernel 4: loss. 1 wave/row, shuffle-only (no LDS, no barriers).
// ---------------------------------------------------------------------------
__global__ __launch_bounds__(64) void loss_kernel(
    const float* __restrict__ logits, const float* __restrict__ labels,
    float* __restrict__ out)
{
    const int bm = blockIdx.x;
    const int i  = bm & (M_ - 1);
    const int lane = threadIdx.x;

    float val[4];
    #pragma unroll
    for (int qq = 0; qq < 4; ++qq) {
        const int j = qq * 64 + lane;
        val[qq] = (j < i) ? logits[(size_t)bm * M_ + j]
                          : ((j == i) ? 0.0f : -1e30f);
    }
    float m = fmaxf(fmaxf(val[0], val[1]), fmaxf(val[2], val[3]));
    #pragma unroll
    for (int off = 32; off >= 1; off >>= 1) m = fmaxf(m, __shfl_xor(m, off));

    float s = 0.f;
    float e[4];
    #pragma unroll
    for (int qq = 0; qq < 4; ++qq) {
        const int j = qq * 64 + lane;
        e[qq] = (j <= i) ? expf(val[qq] - m) : 0.0f;
        s += e[qq];
    }
    #pragma unroll
    for (int off = 32; off >= 1; off >>= 1) s += __shfl_xor(s, off);
    const float inv_s = 1.0f / s;

    float rs = 0.f;
    #pragma unroll
    for (int qq = 0; qq < 4; ++qq) {
        const int j = qq * 64 + lane;
        float prob = (j <= i) ? (e[qq] * inv_s) : -1000.0f;
        float tv = prob * labels[(size_t)bm * M_ + j];
        rs += fminf(fmaxf(tv, 1e-8f), 1.0f - 1e-8f);
    }
    #pragma unroll
    for (int off = 32; off >= 1; off >>= 1) rs += __shfl_xor(rs, off);

    if (lane == 0) atomicAdd(out, -logf(rs));
}

// ---------------------------------------------------------------------------
extern "C" void kernel_launch(void* const* d_in, const int* in_sizes, int n_in,
                              void* d_out, int out_size, void* d_ws, size_t ws_size,
                              hipStream_t stream)
{
    const float* hidden = (const float*)d_in[0];
    const int*   sutt   = (const int*)d_in[1];
    const int*   sstart = (const int*)d_in[2];
    const int*   send   = (const int*)d_in[3];
    const float* labels = (const float*)d_in[4];
    const float* W1     = (const float*)d_in[5];
    const float* b1     = (const float*)d_in[6];
    const float* W2     = (const float*)d_in[7];
    const float* b2     = (const float*)d_in[8];
    const float* W3     = (const float*)d_in[9];
    const float* b3     = (const float*)d_in[10];

    float* ws = (float*)d_ws;
    float*    hiF     = ws;                          // [1024][160]
    float*    hjT     = ws + 163840;                 // [160][1024]
    float*    logits  = ws + 327680;                 // 262144
    float2*   bw      = (float2*)(ws + 589824);      // 160 float2
    _Float16* pooledh = (_Float16*)(ws + 590144);    // 786432 f16
    _Float16* W1cs16  = (_Float16*)(ws + 983360);    // 122880 f16
    _Float16* W2s16   = (_Float16*)(ws + 1106240);   // 25600 f16
    _Float16* W1abs   = (_Float16*)(ws + 1119040);   // 245760 f16
    _Float16* pjF16   = (_Float16*)(ws + 1241920);   // 786432 f16 (1.5 MB)
    float* out = (float*)d_out;

    hipMemsetAsync(d_out, 0, sizeof(float), stream);

    prep_pool_kernel<<<dim3(1796), 256, 0, stream>>>(
        W1, W2, b2, W3, hidden, sutt, sstart, send,
        W1cs16, W2s16, W1abs, bw, pooledh);
    hihj_kernel<<<dim3(448), 256, 0, stream>>>(pooledh, b1, W1abs,
                                               hiF, hjT, pjF16);
    pair_mlp_kernel<<<dim3(576 * B_), 256, 0, stream>>>(pooledh, pjF16, hiF, hjT,
                                                        W1cs16, W2s16, bw, b3, logits);
    loss_kernel<<<dim3(B_ * M_), 64, 0, stream>>>(logits, labels, out);
}